// Round 14
// baseline (264.337 us; speedup 1.0000x reference)
//
#include <hip/hip_runtime.h>

// StockLSTM R14 = R13 + ILP restructure (register-neutral):
//  - a1/a2 MFMA chains interleaved (two independent dep-chains hide the
//    ~20cyc dependent-MFMA latency),
//  - both cell updates fused into cell_update2: 8 independent exp2 batched
//    to fill the quarter-rate trans pipe; float2 pairs for v_pk packing,
//  - x fragment read issued first (no barrier dependency).
// Walls (measured): 64-VGPR allocator cap, grid=256 -> 1 block/CU,
// 1 barrier/step minimum. Floor estimate ~1200cyc/step vs 2020 now.

#define TT   256
#define II   5
#define HH   64
#define OO   25
#define MT   16
#define NTHR 1024
#define XP   520        // x chunk row stride (ushorts): 64*8 + 8 skew
#define HSZ  1024       // h parity block: 64 k * 16 batch shorts
#define HF   65

typedef __attribute__((ext_vector_type(8))) short  short8;
typedef __attribute__((ext_vector_type(4))) float  floatx4;

#define MFMA(a, b, c) __builtin_amdgcn_mfma_f32_16x16x32_bf16(a, b, c, 0, 0, 0)

__device__ __forceinline__ float frcp(float x) { return __builtin_amdgcn_rcpf(x); }
__device__ __forceinline__ float fexp2(float x) { return __builtin_amdgcn_exp2f(x); }
__device__ __forceinline__ unsigned short bf16_rne(float f) {
    unsigned int u = __builtin_bit_cast(unsigned int, f);
    u += 0x7FFFu + ((u >> 16) & 1u);
    return (unsigned short)(u >> 16);
}
// gates arrive PRE-SCALED: idx 0,1,3 = -log2e*z ; idx 2 = +2log2e*z
__device__ __forceinline__ float cell_update(const floatx4& g, float& c) {
    const float gi = frcp(1.f + fexp2(g[0]));
    const float gf = frcp(1.f + fexp2(g[1]));
    const float gz = fmaf(-2.f, frcp(1.f + fexp2(g[2])), 1.f);
    const float go = frcp(1.f + fexp2(g[3]));
    c = fmaf(gf, c, gi * gz);
    const float tc = fmaf(-2.f, frcp(1.f + fexp2(c * 2.885390082f)), 1.f);
    return go * tc;
}
// fused pair: batches all 8 exp2 up front, float2 pairs for pk-packing
__device__ __forceinline__ float2 cell_update2(const floatx4& gA, const floatx4& gB,
                                               float& cA, float& cB) {
    const float eiA = fexp2(gA[0]), eiB = fexp2(gB[0]);
    const float efA = fexp2(gA[1]), efB = fexp2(gB[1]);
    const float ezA = fexp2(gA[2]), ezB = fexp2(gB[2]);
    const float eoA = fexp2(gA[3]), eoB = fexp2(gB[3]);
    const float giA = frcp(1.f + eiA), giB = frcp(1.f + eiB);
    const float gfA = frcp(1.f + efA), gfB = frcp(1.f + efB);
    const float gzA = fmaf(-2.f, frcp(1.f + ezA), 1.f);
    const float gzB = fmaf(-2.f, frcp(1.f + ezB), 1.f);
    const float goA = frcp(1.f + eoA), goB = frcp(1.f + eoB);
    cA = fmaf(gfA, cA, giA * gzA);
    cB = fmaf(gfB, cB, giB * gzB);
    const float etA = fexp2(cA * 2.885390082f);
    const float etB = fexp2(cB * 2.885390082f);
    const float tcA = fmaf(-2.f, frcp(1.f + etA), 1.f);
    const float tcB = fmaf(-2.f, frcp(1.f + etB), 1.f);
    return make_float2(goA * tcA, goB * tcB);
}

__global__ __attribute__((amdgpu_flat_work_group_size(1024, 1024),
                          amdgpu_waves_per_eu(4, 4)))
void lstm_mfmaA(const float* __restrict__ x,
                const float* __restrict__ Wih0, const float* __restrict__ Whh0,
                const float* __restrict__ bih0, const float* __restrict__ bhh0,
                const float* __restrict__ Wih1, const float* __restrict__ Whh1,
                const float* __restrict__ bih1, const float* __restrict__ bhh1,
                const float* __restrict__ Wfc,  const float* __restrict__ bfc,
                float* __restrict__ out)
{
    __shared__ __align__(16) unsigned short xhi[MT * XP];     // 16.6 KB
    __shared__ __align__(16) unsigned short h1hi[2 * HSZ];    // 4 KB each
    __shared__ __align__(16) unsigned short h2hi[2 * HSZ];
    __shared__ __align__(16) float          h2f[MT * HF];

    const int tid   = threadIdx.x;
    const int w     = tid >> 6;
    const int lane  = tid & 63;
    const int b     = lane & 15;      // batch col
    const int q     = lane >> 4;      // k-slice / C row-quad
    const int jmine = 4 * w + q;
    const int hw_off = ((jmine >> 3) * 16 + b) * 8 + (jmine & 7);
    const int ro     = lane * 8;      // fragment read offset: lane*16B

    // ---------------- weights (bf16), nonlinearity scale folded in ----------------
    short8 A1h[2];   // Whh0 k-chunks
    short8 A2h[4];   // 0,1: Wih1 (h1 side); 2,3: Whh1 (h2 side)
    short8 Axwh;     // Wih0: k<II valid, rest exact zero
    {
        const int rr = lane & 15;
        const int g  = (rr & 3) * 64 + 4 * w + (rr >> 2);
        const float sc = ((rr & 3) == 2) ? 2.885390082f : -1.442695041f;
        #pragma unroll
        for (int c = 0; c < 2; ++c)
            #pragma unroll
            for (int jj = 0; jj < 8; ++jj)
                A1h[c][jj] = (short)bf16_rne(sc * Whh0[g * HH + c * 32 + q * 8 + jj]);
        #pragma unroll
        for (int c = 0; c < 4; ++c)
            #pragma unroll
            for (int jj = 0; jj < 8; ++jj) {
                const int k = c * 32 + q * 8 + jj;
                float wv = (k < HH) ? Wih1[g * HH + k] : Whh1[g * HH + (k - HH)];
                A2h[c][jj] = (short)bf16_rne(sc * wv);
            }
        #pragma unroll
        for (int jj = 0; jj < 8; ++jj) {
            const int k = q * 8 + jj;
            Axwh[jj] = (k < II) ? (short)bf16_rne(sc * Wih0[g * II + k]) : (short)0;
        }
    }
    float bias1[4], bias2[4];
    #pragma unroll
    for (int r = 0; r < 4; ++r) {
        const int g = r * 64 + jmine;
        const float sc = (r == 2) ? 2.885390082f : -1.442695041f;
        bias1[r] = sc * (bih0[g] + bhh0[g]);
        bias2[r] = sc * (bih1[g] + bhh1[g]);
    }

    // ---------------- zero LDS ----------------
    for (int i = tid; i < MT * XP / 2; i += NTHR)
        ((unsigned int*)xhi)[i] = 0u;
    for (int i = tid; i < HSZ; i += NTHR) {
        ((unsigned int*)h1hi)[i] = 0u;
        ((unsigned int*)h2hi)[i] = 0u;
    }
    float c1 = 0.f, c2 = 0.f;
    __syncthreads();

    const int blockBase = blockIdx.x * MT;

    auto refill_x = [&](int t0) {
        const int rb = tid >> 6, dt = tid & 63;
        const float* src = x + ((size_t)(blockBase + rb) * TT + t0 + dt) * II;
        unsigned short* ph = xhi + rb * XP + dt * 8;
        #pragma unroll
        for (int ii = 0; ii < II; ++ii)
            ph[ii] = bf16_rne(src[ii]);
    };

    // ================= prologue: L1(0) =================
    refill_x(0);
    __syncthreads();
    {
        short8 Bxh = *(const short8*)(xhi + b * XP);       // dt = 0
        floatx4 a1 = {bias1[0], bias1[1], bias1[2], bias1[3]};
        a1 = MFMA(Axwh, Bxh, a1);
        const float h = cell_update(a1, c1);
        h1hi[0 * HSZ + hw_off] = bf16_rne(h);              // parity 0
    }
    __syncthreads();

    // x read pointer: STEP(i) reads dt=(i+1)&63; starts at dt=1.
    const unsigned short* xptr = xhi + b * XP + 8;

    // ================= merged main loop, unrolled by 2 =================
#define STEP_BODY(WP, RP)                                                     \
    {                                                                         \
        short8 Bxh  = *(const short8*)(xptr);                                 \
        xptr += 8;                                                            \
        short8 H1h0 = *(const short8*)(h1hi + (WP) * HSZ + ro);               \
        short8 H1h1 = *(const short8*)(h1hi + (WP) * HSZ + 512 + ro);         \
        short8 H2h0 = *(const short8*)(h2hi + (RP) * HSZ + ro);               \
        short8 H2h1 = *(const short8*)(h2hi + (RP) * HSZ + 512 + ro);         \
        floatx4 a2 = {bias2[0], bias2[1], bias2[2], bias2[3]};                \
        floatx4 a1 = {bias1[0], bias1[1], bias1[2], bias1[3]};                \
        a1 = MFMA(Axwh,   Bxh,  a1);                                          \
        a2 = MFMA(A2h[0], H1h0, a2);                                          \
        a1 = MFMA(A1h[0], H1h0, a1);                                          \
        a2 = MFMA(A2h[1], H1h1, a2);                                          \
        a1 = MFMA(A1h[1], H1h1, a1);                                          \
        a2 = MFMA(A2h[2], H2h0, a2);                                          \
        a2 = MFMA(A2h[3], H2h1, a2);                                          \
        float2 hh = cell_update2(a2, a1, c2, c1);                             \
        h2hi[(WP) * HSZ + hw_off] = bf16_rne(hh.x);                           \
        h1hi[(RP) * HSZ + hw_off] = bf16_rne(hh.y);                           \
        __syncthreads();                                                      \
    }

    for (int i = 0; i < 254; i += 2) {
        STEP_BODY(0, 1)                      // interval i   (even)
        if (((i + 2) & 63) == 0) {           // refill before interval i+1
            refill_x(i + 2);
            xptr = xhi + b * XP;             // next read is dt = 0
            __syncthreads();
        }
        STEP_BODY(1, 0)                      // interval i+1 (odd)
    }
    STEP_BODY(0, 1)                          // interval 254
#undef STEP_BODY

    // ================= epilogue: L2(255) =================
    {
        short8 H1h0 = *(const short8*)(h1hi + 1 * HSZ + ro);
        short8 H1h1 = *(const short8*)(h1hi + 1 * HSZ + 512 + ro);
        short8 H2h0 = *(const short8*)(h2hi + 0 * HSZ + ro);
        short8 H2h1 = *(const short8*)(h2hi + 0 * HSZ + 512 + ro);
        floatx4 a2 = {bias2[0], bias2[1], bias2[2], bias2[3]};
        a2 = MFMA(A2h[0], H1h0, a2);
        a2 = MFMA(A2h[1], H1h1, a2);
        a2 = MFMA(A2h[2], H2h0, a2);
        a2 = MFMA(A2h[3], H2h1, a2);
        const float h = cell_update(a2, c2);
        h2f[b * HF + jmine] = h;
    }
    __syncthreads();

    // ================= FC epilogue =================
    if (tid < MT * OO) {
        const int bb = tid / OO, o = tid - bb * OO;
        float acc = bfc[o];
        const float* wr = Wfc + o * HH;
        const float* hr = h2f + bb * HF;
        #pragma unroll
        for (int j = 0; j < HH; ++j) acc += wr[j] * hr[j];
        out[((size_t)blockIdx.x * MT + bb) * OO + o] = acc;
    }
}

extern "C" void kernel_launch(void* const* d_in, const int* in_sizes, int n_in,
                              void* d_out, int out_size, void* d_ws, size_t ws_size,
                              hipStream_t stream) {
    const float* x    = (const float*)d_in[0];
    const float* Wih0 = (const float*)d_in[1];
    const float* Whh0 = (const float*)d_in[2];
    const float* bih0 = (const float*)d_in[3];
    const float* bhh0 = (const float*)d_in[4];
    const float* Wih1 = (const float*)d_in[5];
    const float* Whh1 = (const float*)d_in[6];
    const float* bih1 = (const float*)d_in[7];
    const float* bhh1 = (const float*)d_in[8];
    const float* Wfc  = (const float*)d_in[9];
    const float* bfc  = (const float*)d_in[10];
    float* out = (float*)d_out;

    dim3 grid(4096 / MT), block(NTHR);
    lstm_mfmaA<<<grid, block, 0, stream>>>(x, Wih0, Whh0, bih0, bhh0,
                                           Wih1, Whh1, bih1, bhh1,
                                           Wfc, bfc, out);
}